// Round 1
// baseline (3218.650 us; speedup 1.0000x reference)
//
#include <hip/hip_runtime.h>

#define TPB 256

// ---------------- CSR build ----------------

__global__ void k_count(const int* __restrict__ dstA, const float* __restrict__ ef,
                        int* __restrict__ cnt, float* __restrict__ lsum, int E) {
    int e = blockIdx.x * blockDim.x + threadIdx.x;
    if (e >= E) return;
    int d = dstA[e];
    atomicAdd(&cnt[d], 1);
    atomicAdd(&lsum[d * 3 + 0], ef[e * 3 + 0]);
    atomicAdd(&lsum[d * 3 + 1], ef[e * 3 + 1]);
    atomicAdd(&lsum[d * 3 + 2], ef[e * 3 + 2]);
}

__global__ void k_loopdiv(float* __restrict__ lsum, const int* __restrict__ cnt, int N) {
    int i = blockIdx.x * blockDim.x + threadIdx.x;
    if (i >= N) return;
    float inv = 1.0f / (float)max(cnt[i], 1);
    lsum[i * 3 + 0] *= inv;
    lsum[i * 3 + 1] *= inv;
    lsum[i * 3 + 2] *= inv;
}

// exclusive scan of (cnt[i]+1) over N elements, single block
__global__ void k_scan(const int* __restrict__ cnt, int* __restrict__ rowptr, int N) {
    __shared__ int part[TPB];
    __shared__ int offs[TPB];
    int tid = threadIdx.x;
    int chunk = (N + TPB - 1) / TPB;
    int beg = tid * chunk;
    int end = min(beg + chunk, N);
    int s = 0;
    for (int i = beg; i < end; ++i) s += cnt[i] + 1;
    part[tid] = s;
    __syncthreads();
    if (tid == 0) {
        int acc = 0;
        for (int i = 0; i < TPB; ++i) { offs[i] = acc; acc += part[i]; }
    }
    __syncthreads();
    int acc = offs[tid];
    for (int i = beg; i < end; ++i) { rowptr[i] = acc; acc += cnt[i] + 1; }
    if (end == N) rowptr[N] = acc;  // all qualifying threads write the same total
}

__global__ void k_fill(const int* __restrict__ srcA, const int* __restrict__ dstA,
                       const int* __restrict__ rowptr, int* __restrict__ fill,
                       int* __restrict__ csrc, int* __restrict__ ceid, int* __restrict__ cdst,
                       int E) {
    int e = blockIdx.x * blockDim.x + threadIdx.x;
    if (e >= E) return;
    int d = dstA[e];
    int pos = atomicAdd(&fill[d], 1);
    int slot = rowptr[d] + pos;
    csrc[slot] = srcA[e];
    ceid[slot] = e;
    cdst[slot] = d;
}

__global__ void k_selfloop(const int* __restrict__ rowptr, const int* __restrict__ cnt,
                           int* __restrict__ csrc, int* __restrict__ ceid, int* __restrict__ cdst,
                           int N, int E) {
    int i = blockIdx.x * blockDim.x + threadIdx.x;
    if (i >= N) return;
    int slot = rowptr[i] + cnt[i];  // self-loop in last slot of the row
    csrc[slot] = i;
    ceid[slot] = E + i;
    cdst[slot] = i;
}

// ---------------- per-layer kernels ----------------

// xl = xin@Wl + bl ; xr = xin@Wr + br
__global__ void k_lin(const float* __restrict__ xin,
                      const float* __restrict__ wl, const float* __restrict__ bl,
                      const float* __restrict__ wr, const float* __restrict__ br,
                      float* __restrict__ xl, float* __restrict__ xr,
                      int N, int F, int HC) {
    int t = blockIdx.x * blockDim.x + threadIdx.x;
    if (t >= N * HC) return;
    int i = t / HC, o = t % HC;
    float al = bl[o], ar = br[o];
    const float* xrow = xin + (size_t)i * F;
    for (int k = 0; k < F; ++k) {
        float xv = xrow[k];
        al = fmaf(xv, wl[k * HC + o], al);
        ar = fmaf(xv, wr[k * HC + o], ar);
    }
    xl[t] = al;
    xr[t] = ar;
}

// logit[slot][h] = sum_c att[h,c] * lrelu(xl[src,h,c] + xr[dst,h,c] + (eattr@We)[h,c])
// HC consecutive lanes handle one slot -> coalesced gathers; shfl_xor reduce over C.
__global__ void k_logit(const int* __restrict__ csrc, const int* __restrict__ cdst,
                        const int* __restrict__ ceid,
                        const float* __restrict__ xl, const float* __restrict__ xr,
                        const float* __restrict__ ef, const float* __restrict__ lattr,
                        const float* __restrict__ we, const float* __restrict__ att,
                        float* __restrict__ logit, int Etot, int E, int H, int C) {
    int HC = H * C;
    int t = blockIdx.x * blockDim.x + threadIdx.x;
    if (t >= Etot * HC) return;
    int slot = t / HC;
    int o = t % HC;
    int src = csrc[slot], dst = cdst[slot], e = ceid[slot];
    const float* f3 = (e < E) ? (ef + (size_t)e * 3) : (lattr + (size_t)(e - E) * 3);
    float ep = f3[0] * we[o] + f3[1] * we[HC + o] + f3[2] * we[2 * HC + o];
    float s = xl[(size_t)src * HC + o] + xr[(size_t)dst * HC + o] + ep;
    s = (s > 0.f) ? s : 0.2f * s;
    float v = att[o] * s;
    for (int m = C >> 1; m; m >>= 1) v += __shfl_xor(v, m);
    if ((o & (C - 1)) == 0) logit[(size_t)slot * H + (o / C)] = v;
}

// per (node, head): segment softmax over the node's CSR row, normalized in place
__global__ void k_softmax(const int* __restrict__ rowptr, float* __restrict__ logit,
                          int N, int H) {
    int t = blockIdx.x * blockDim.x + threadIdx.x;
    if (t >= N * H) return;
    int i = t / H, h = t % H;
    int b = rowptr[i], e = rowptr[i + 1];
    float m = -1e30f;
    for (int s = b; s < e; ++s) m = fmaxf(m, logit[(size_t)s * H + h]);
    float den = 0.f;
    for (int s = b; s < e; ++s) {
        float p = expf(logit[(size_t)s * H + h] - m);
        logit[(size_t)s * H + h] = p;
        den += p;
    }
    float inv = 1.0f / den;
    for (int s = b; s < e; ++s) logit[(size_t)s * H + h] *= inv;
}

// out[i,o] = relu( sum_slots a[slot,h] * xl[src,o] + cb[o] )
__global__ void k_agg(const int* __restrict__ rowptr, const int* __restrict__ csrc,
                      const float* __restrict__ a, const float* __restrict__ xl,
                      const float* __restrict__ cb, float* __restrict__ hout,
                      int N, int H, int C) {
    int HC = H * C;
    int t = blockIdx.x * blockDim.x + threadIdx.x;
    if (t >= N * HC) return;
    int i = t / HC, o = t % HC;
    int h = o / C;
    int b = rowptr[i], e = rowptr[i + 1];
    float acc = 0.f;
    for (int s = b; s < e; ++s)
        acc = fmaf(a[(size_t)s * H + h], xl[(size_t)csrc[s] * HC + o], acc);
    acc += cb[o];
    hout[t] = fmaxf(acc, 0.f);
}

// ---------------- pooling + final linear ----------------

__global__ void k_pool(const float* __restrict__ h, const int* __restrict__ batch,
                       float* __restrict__ psum, int* __restrict__ pcnt, int N) {
    int t = blockIdx.x * blockDim.x + threadIdx.x;
    if (t >= N * 64) return;
    int i = t >> 6, o = t & 63;
    int g = batch[i];
    atomicAdd(&psum[g * 64 + o], h[t]);
    if (o == 0) atomicAdd(&pcnt[g], 1);
}

__global__ void k_final(const float* __restrict__ psum, const int* __restrict__ pcnt,
                        const float* __restrict__ wlin, const float* __restrict__ blin,
                        float* __restrict__ out, int G) {
    int t = blockIdx.x * blockDim.x + threadIdx.x;
    if (t >= G * 32) return;
    int g = t / 32, j = t % 32;
    float acc = 0.f;
    for (int k = 0; k < 64; ++k) acc = fmaf(psum[g * 64 + k], wlin[k * 32 + j], acc);
    float inv = 1.0f / (float)max(pcnt[g], 1);
    out[t] = acc * inv + blin[j];
}

// ---------------- host ----------------

extern "C" void kernel_launch(void* const* d_in, const int* in_sizes, int n_in,
                              void* d_out, int out_size, void* d_ws, size_t ws_size,
                              hipStream_t stream) {
    const float* x = (const float*)d_in[0];
    const int* ei = (const int*)d_in[1];
    const float* ef = (const float*)d_in[2];
    const int* batch = (const int*)d_in[3];

    int N = in_sizes[0] / 5;
    int E = in_sizes[1] / 2;
    int G = out_size / 32;
    int Etot = E + N;
    const int* srcA = ei;
    const int* dstA = ei + E;

    // workspace layout
    char* w = (char*)d_ws;
    size_t off = 0;
    auto A = [&](size_t bytes) -> void* {
        void* p = w + off;
        off = (off + bytes + 255) & ~(size_t)255;
        return p;
    };
    // zero-init region (one memset): cnt0, fill, lsum, psum, pcnt
    int* cnt0 = (int*)A((size_t)N * 4);
    int* fill = (int*)A((size_t)N * 4);
    float* lsum = (float*)A((size_t)N * 3 * 4);
    float* psum = (float*)A((size_t)G * 64 * 4);
    int* pcnt = (int*)A((size_t)G * 4);
    size_t zbytes = off;
    int* rowptr = (int*)A((size_t)(N + 1) * 4);
    int* csrc = (int*)A((size_t)Etot * 4);
    int* ceid = (int*)A((size_t)Etot * 4);
    int* cdst = (int*)A((size_t)Etot * 4);
    float* xl = (float*)A((size_t)N * 128 * 4);
    float* xr = (float*)A((size_t)N * 128 * 4);
    float* h0 = (float*)A((size_t)N * 128 * 4);
    float* h1 = (float*)A((size_t)N * 128 * 4);
    float* logit = (float*)A((size_t)Etot * 4 * 4);

    hipMemsetAsync(d_ws, 0, zbytes, stream);

    dim3 B(TPB);
    k_count<<<(E + TPB - 1) / TPB, B, 0, stream>>>(dstA, ef, cnt0, lsum, E);
    k_loopdiv<<<(N + TPB - 1) / TPB, B, 0, stream>>>(lsum, cnt0, N);
    k_scan<<<1, B, 0, stream>>>(cnt0, rowptr, N);
    k_fill<<<(E + TPB - 1) / TPB, B, 0, stream>>>(srcA, dstA, rowptr, fill, csrc, ceid, cdst, E);
    k_selfloop<<<(N + TPB - 1) / TPB, B, 0, stream>>>(rowptr, cnt0, csrc, ceid, cdst, N, E);

    const int Fs[4] = {5, 64, 128, 128};
    const int Hs[4] = {4, 4, 4, 2};
    const int Cs[4] = {16, 32, 32, 32};
    float* houts[4] = {h0, h1, h0, h1};

    const float* hin = x;
    for (int l = 0; l < 4; ++l) {
        const float* wl  = (const float*)d_in[4 + l * 7 + 0];
        const float* bl  = (const float*)d_in[4 + l * 7 + 1];
        const float* wr  = (const float*)d_in[4 + l * 7 + 2];
        const float* br  = (const float*)d_in[4 + l * 7 + 3];
        const float* we  = (const float*)d_in[4 + l * 7 + 4];
        const float* att = (const float*)d_in[4 + l * 7 + 5];
        const float* cb  = (const float*)d_in[4 + l * 7 + 6];
        int F = Fs[l], H = Hs[l], C = Cs[l], HC = H * C;

        long long nlin = (long long)N * HC;
        k_lin<<<(unsigned)((nlin + TPB - 1) / TPB), B, 0, stream>>>(hin, wl, bl, wr, br,
                                                                    xl, xr, N, F, HC);
        long long nlg = (long long)Etot * HC;
        k_logit<<<(unsigned)((nlg + TPB - 1) / TPB), B, 0, stream>>>(csrc, cdst, ceid, xl, xr,
                                                                     ef, lsum, we, att, logit,
                                                                     Etot, E, H, C);
        k_softmax<<<(N * H + TPB - 1) / TPB, B, 0, stream>>>(rowptr, logit, N, H);
        k_agg<<<(unsigned)((nlin + TPB - 1) / TPB), B, 0, stream>>>(rowptr, csrc, logit, xl,
                                                                    cb, houts[l], N, H, C);
        hin = houts[l];
    }

    k_pool<<<((long long)N * 64 + TPB - 1) / TPB, B, 0, stream>>>(hin, batch, psum, pcnt, N);
    k_final<<<(G * 32 + TPB - 1) / TPB, B, 0, stream>>>(psum, pcnt,
                                                        (const float*)d_in[32],
                                                        (const float*)d_in[33],
                                                        (float*)d_out, G);
}

// Round 2
// 1788.623 us; speedup vs baseline: 1.7995x; 1.7995x over previous
//
#include <hip/hip_runtime.h>
#include <hip/hip_fp16.h>

#define TPB 256

// ---------------- CSR build ----------------

__global__ void k_count(const int* __restrict__ dstA, const float* __restrict__ ef,
                        int* __restrict__ cnt, float* __restrict__ lsum, int E) {
    int e = blockIdx.x * blockDim.x + threadIdx.x;
    if (e >= E) return;
    int d = dstA[e];
    atomicAdd(&cnt[d], 1);
    atomicAdd(&lsum[d * 3 + 0], ef[e * 3 + 0]);
    atomicAdd(&lsum[d * 3 + 1], ef[e * 3 + 1]);
    atomicAdd(&lsum[d * 3 + 2], ef[e * 3 + 2]);
}

__global__ void k_loopdiv(float* __restrict__ lsum, const int* __restrict__ cnt, int N) {
    int i = blockIdx.x * blockDim.x + threadIdx.x;
    if (i >= N) return;
    float inv = 1.0f / (float)max(cnt[i], 1);
    lsum[i * 3 + 0] *= inv;
    lsum[i * 3 + 1] *= inv;
    lsum[i * 3 + 2] *= inv;
}

// exclusive scan of (cnt[i]+1) over N elements, single block
__global__ void k_scan(const int* __restrict__ cnt, int* __restrict__ rowptr, int N) {
    __shared__ int part[TPB];
    __shared__ int offs[TPB];
    int tid = threadIdx.x;
    int chunk = (N + TPB - 1) / TPB;
    int beg = tid * chunk;
    int end = min(beg + chunk, N);
    int s = 0;
    for (int i = beg; i < end; ++i) s += cnt[i] + 1;
    part[tid] = s;
    __syncthreads();
    if (tid == 0) {
        int acc = 0;
        for (int i = 0; i < TPB; ++i) { offs[i] = acc; acc += part[i]; }
    }
    __syncthreads();
    int acc = offs[tid];
    for (int i = beg; i < end; ++i) { rowptr[i] = acc; acc += cnt[i] + 1; }
    if (end == N) rowptr[N] = acc;
}

__global__ void k_fill(const int* __restrict__ srcA, const int* __restrict__ dstA,
                       const float* __restrict__ ef,
                       const int* __restrict__ rowptr, int* __restrict__ fill,
                       int* __restrict__ csrc, float* __restrict__ cef, int E) {
    int e = blockIdx.x * blockDim.x + threadIdx.x;
    if (e >= E) return;
    int d = dstA[e];
    int pos = atomicAdd(&fill[d], 1);
    int slot = rowptr[d] + pos;
    csrc[slot] = srcA[e];
    cef[slot * 3 + 0] = ef[e * 3 + 0];
    cef[slot * 3 + 1] = ef[e * 3 + 1];
    cef[slot * 3 + 2] = ef[e * 3 + 2];
}

__global__ void k_selfloop(const int* __restrict__ rowptr, const int* __restrict__ cnt,
                           const float* __restrict__ lsum,
                           int* __restrict__ csrc, float* __restrict__ cef, int N) {
    int i = blockIdx.x * blockDim.x + threadIdx.x;
    if (i >= N) return;
    int slot = rowptr[i] + cnt[i];  // self-loop in last slot of the row
    csrc[slot] = i;
    cef[slot * 3 + 0] = lsum[i * 3 + 0];
    cef[slot * 3 + 1] = lsum[i * 3 + 1];
    cef[slot * 3 + 2] = lsum[i * 3 + 2];
}

// ---------------- per-layer kernels ----------------

// xl (fp16) = xin@Wl + bl ; xr (fp32) = xin@Wr + br
__global__ void k_lin(const float* __restrict__ xin,
                      const float* __restrict__ wl, const float* __restrict__ bl,
                      const float* __restrict__ wr, const float* __restrict__ br,
                      __half* __restrict__ xl16, float* __restrict__ xr,
                      int N, int F, int HC) {
    int t = blockIdx.x * blockDim.x + threadIdx.x;
    if (t >= N * HC) return;
    int i = t / HC, o = t % HC;
    float al = bl[o], ar = br[o];
    const float* xrow = xin + (size_t)i * F;
    for (int k = 0; k < F; ++k) {
        float xv = xrow[k];
        al = fmaf(xv, wl[k * HC + o], al);
        ar = fmaf(xv, wr[k * HC + o], ar);
    }
    xl16[t] = __float2half(al);
    xr[t] = ar;
}

// Fused GATv2: per dst node, online-softmax over its CSR row, aggregate in regs.
// One wave handles NPW nodes; each node gets PAIRS=HC/2 lanes (channels 2p,2p+1).
template <int H, int C>
__global__ void k_fused(const int* __restrict__ rowptr, const int* __restrict__ csrc,
                        const float* __restrict__ cef,
                        const __half* __restrict__ xl16, const float* __restrict__ xr,
                        const float* __restrict__ we, const float* __restrict__ att,
                        const float* __restrict__ cb, float* __restrict__ hout, int N) {
    constexpr int HC = H * C;
    constexpr int PAIRS = HC / 2;   // lanes per node
    constexpr int NPW = 64 / PAIRS; // nodes per wave
    int wave = (blockIdx.x * blockDim.x + threadIdx.x) >> 6;
    int lane = threadIdx.x & 63;
    int g = lane / PAIRS;
    int p = lane % PAIRS;
    int node = wave * NPW + g;
    bool act = node < N;

    int o0 = 2 * p, o1 = 2 * p + 1;
    float xr0 = 0.f, xr1 = 0.f;
    int b = 0, len = 0;
    if (act) {
        xr0 = xr[(size_t)node * HC + o0];
        xr1 = xr[(size_t)node * HC + o1];
        b = rowptr[node];
        len = rowptr[node + 1] - b;
    }
    float w0a = we[o0], w0b = we[HC + o0], w0c = we[2 * HC + o0];
    float w1a = we[o1], w1b = we[HC + o1], w1c = we[2 * HC + o1];
    float at0 = att[o0], at1 = att[o1];

    float m_run = -1e30f, den = 0.f, acc0 = 0.f, acc1 = 0.f;

    for (int k = 0; k < len; ++k) {
        int s = b + k;
        int src = csrc[s];
        float f0 = cef[s * 3 + 0], f1 = cef[s * 3 + 1], f2 = cef[s * 3 + 2];
        __half2 hv = *(reinterpret_cast<const __half2*>(xl16 + (size_t)src * HC) + p);
        float2 xv = __half22float2(hv);
        float s0 = xv.x + xr0 + f0 * w0a + f1 * w0b + f2 * w0c;
        float s1 = xv.y + xr1 + f0 * w1a + f1 * w1b + f2 * w1c;
        s0 = (s0 > 0.f) ? s0 : 0.2f * s0;
        s1 = (s1 > 0.f) ? s1 : 0.2f * s1;
        float partial = at0 * s0 + at1 * s1;
        #pragma unroll
        for (int mk = 1; mk < C / 2; mk <<= 1) partial += __shfl_xor(partial, mk);
        float L = partial;  // logit, replicated across the head's C/2 lanes
        float nm = fmaxf(m_run, L);
        float sc = __expf(m_run - nm);
        float pe = __expf(L - nm);
        den = den * sc + pe;
        acc0 = acc0 * sc + pe * xv.x;
        acc1 = acc1 * sc + pe * xv.y;
        m_run = nm;
    }

    if (act) {
        float inv = 1.0f / den;  // every node has a self-loop -> den > 0
        float r0 = fmaxf(acc0 * inv + cb[o0], 0.f);
        float r1 = fmaxf(acc1 * inv + cb[o1], 0.f);
        *reinterpret_cast<float2*>(hout + (size_t)node * HC + o0) = make_float2(r0, r1);
    }
}

// ---------------- pooling + final linear ----------------

__global__ void k_pool(const float* __restrict__ h, const int* __restrict__ batch,
                       float* __restrict__ psum, int* __restrict__ pcnt, int N) {
    int t = blockIdx.x * blockDim.x + threadIdx.x;
    if (t >= N * 64) return;
    int i = t >> 6, o = t & 63;
    int g = batch[i];
    atomicAdd(&psum[g * 64 + o], h[t]);
    if (o == 0) atomicAdd(&pcnt[g], 1);
}

__global__ void k_final(const float* __restrict__ psum, const int* __restrict__ pcnt,
                        const float* __restrict__ wlin, const float* __restrict__ blin,
                        float* __restrict__ out, int G) {
    int t = blockIdx.x * blockDim.x + threadIdx.x;
    if (t >= G * 32) return;
    int g = t / 32, j = t % 32;
    float acc = 0.f;
    for (int k = 0; k < 64; ++k) acc = fmaf(psum[g * 64 + k], wlin[k * 32 + j], acc);
    float inv = 1.0f / (float)max(pcnt[g], 1);
    out[t] = acc * inv + blin[j];
}

// ---------------- host ----------------

extern "C" void kernel_launch(void* const* d_in, const int* in_sizes, int n_in,
                              void* d_out, int out_size, void* d_ws, size_t ws_size,
                              hipStream_t stream) {
    const float* x = (const float*)d_in[0];
    const int* ei = (const int*)d_in[1];
    const float* ef = (const float*)d_in[2];
    const int* batch = (const int*)d_in[3];

    int N = in_sizes[0] / 5;
    int E = in_sizes[1] / 2;
    int G = out_size / 32;
    int Etot = E + N;
    const int* srcA = ei;
    const int* dstA = ei + E;

    char* w = (char*)d_ws;
    size_t off = 0;
    auto A = [&](size_t bytes) -> void* {
        void* p = w + off;
        off = (off + bytes + 255) & ~(size_t)255;
        return p;
    };
    // zero-init region: cnt0, fill, lsum, psum, pcnt
    int* cnt0 = (int*)A((size_t)N * 4);
    int* fill = (int*)A((size_t)N * 4);
    float* lsum = (float*)A((size_t)N * 3 * 4);
    float* psum = (float*)A((size_t)G * 64 * 4);
    int* pcnt = (int*)A((size_t)G * 4);
    size_t zbytes = off;
    int* rowptr = (int*)A((size_t)(N + 1) * 4);
    int* csrc = (int*)A((size_t)Etot * 4);
    float* cef = (float*)A((size_t)Etot * 3 * 4);
    __half* xl16 = (__half*)A((size_t)N * 128 * 2);
    float* xr = (float*)A((size_t)N * 128 * 4);
    float* h0 = (float*)A((size_t)N * 128 * 4);
    float* h1 = (float*)A((size_t)N * 128 * 4);

    hipMemsetAsync(d_ws, 0, zbytes, stream);

    dim3 B(TPB);
    k_count<<<(E + TPB - 1) / TPB, B, 0, stream>>>(dstA, ef, cnt0, lsum, E);
    k_loopdiv<<<(N + TPB - 1) / TPB, B, 0, stream>>>(lsum, cnt0, N);
    k_scan<<<1, B, 0, stream>>>(cnt0, rowptr, N);
    k_fill<<<(E + TPB - 1) / TPB, B, 0, stream>>>(srcA, dstA, ef, rowptr, fill, csrc, cef, E);
    k_selfloop<<<(N + TPB - 1) / TPB, B, 0, stream>>>(rowptr, cnt0, lsum, csrc, cef, N);

    const int Fs[4] = {5, 64, 128, 128};
    const int Hs[4] = {4, 4, 4, 2};
    const int Cs[4] = {16, 32, 32, 32};
    float* houts[4] = {h0, h1, h0, h1};

    const float* hin = x;
    for (int l = 0; l < 4; ++l) {
        const float* wl  = (const float*)d_in[4 + l * 7 + 0];
        const float* bl  = (const float*)d_in[4 + l * 7 + 1];
        const float* wr  = (const float*)d_in[4 + l * 7 + 2];
        const float* br  = (const float*)d_in[4 + l * 7 + 3];
        const float* we  = (const float*)d_in[4 + l * 7 + 4];
        const float* att = (const float*)d_in[4 + l * 7 + 5];
        const float* cb  = (const float*)d_in[4 + l * 7 + 6];
        int F = Fs[l], H = Hs[l], C = Cs[l], HC = H * C;

        long long nlin = (long long)N * HC;
        k_lin<<<(unsigned)((nlin + TPB - 1) / TPB), B, 0, stream>>>(hin, wl, bl, wr, br,
                                                                    xl16, xr, N, F, HC);
        int npw = 64 / (HC / 2);
        int waves = (N + npw - 1) / npw;
        int blocks = (waves + 3) / 4;  // 4 waves per 256-thread block
        if (H == 4 && C == 16)
            k_fused<4, 16><<<blocks, B, 0, stream>>>(rowptr, csrc, cef, xl16, xr,
                                                     we, att, cb, houts[l], N);
        else if (H == 4 && C == 32)
            k_fused<4, 32><<<blocks, B, 0, stream>>>(rowptr, csrc, cef, xl16, xr,
                                                     we, att, cb, houts[l], N);
        else
            k_fused<2, 32><<<blocks, B, 0, stream>>>(rowptr, csrc, cef, xl16, xr,
                                                     we, att, cb, houts[l], N);
        hin = houts[l];
    }

    k_pool<<<((long long)N * 64 + TPB - 1) / TPB, B, 0, stream>>>(hin, batch, psum, pcnt, N);
    k_final<<<(G * 32 + TPB - 1) / TPB, B, 0, stream>>>(psum, pcnt,
                                                        (const float*)d_in[32],
                                                        (const float*)d_in[33],
                                                        (float*)d_out, G);
}

// Round 3
// 1125.780 us; speedup vs baseline: 2.8590x; 1.5888x over previous
//
#include <hip/hip_runtime.h>
#include <hip/hip_fp16.h>

#define TPB 256

// ---------------- CSR build ----------------

__global__ void k_count(const int* __restrict__ dstA, const float* __restrict__ ef,
                        int* __restrict__ cnt, float* __restrict__ lsum, int E) {
    int e = blockIdx.x * blockDim.x + threadIdx.x;
    if (e >= E) return;
    int d = dstA[e];
    atomicAdd(&cnt[d], 1);
    atomicAdd(&lsum[d * 3 + 0], ef[e * 3 + 0]);
    atomicAdd(&lsum[d * 3 + 1], ef[e * 3 + 1]);
    atomicAdd(&lsum[d * 3 + 2], ef[e * 3 + 2]);
}

__global__ void k_loopdiv(float* __restrict__ lsum, const int* __restrict__ cnt, int N) {
    int i = blockIdx.x * blockDim.x + threadIdx.x;
    if (i >= N) return;
    float inv = 1.0f / (float)max(cnt[i], 1);
    lsum[i * 3 + 0] *= inv;
    lsum[i * 3 + 1] *= inv;
    lsum[i * 3 + 2] *= inv;
}

// exclusive scan of (cnt[i]+1) over N elements, single block
__global__ void k_scan(const int* __restrict__ cnt, int* __restrict__ rowptr, int N) {
    __shared__ int part[TPB];
    __shared__ int offs[TPB];
    int tid = threadIdx.x;
    int chunk = (N + TPB - 1) / TPB;
    int beg = tid * chunk;
    int end = min(beg + chunk, N);
    int s = 0;
    for (int i = beg; i < end; ++i) s += cnt[i] + 1;
    part[tid] = s;
    __syncthreads();
    if (tid == 0) {
        int acc = 0;
        for (int i = 0; i < TPB; ++i) { offs[i] = acc; acc += part[i]; }
    }
    __syncthreads();
    int acc = offs[tid];
    for (int i = beg; i < end; ++i) { rowptr[i] = acc; acc += cnt[i] + 1; }
    if (end == N) rowptr[N] = acc;
}

__global__ void k_fill(const int* __restrict__ srcA, const int* __restrict__ dstA,
                       const float* __restrict__ ef,
                       const int* __restrict__ rowptr, int* __restrict__ fill,
                       int* __restrict__ csrc, float* __restrict__ cef, int E) {
    int e = blockIdx.x * blockDim.x + threadIdx.x;
    if (e >= E) return;
    int d = dstA[e];
    int pos = atomicAdd(&fill[d], 1);
    int slot = rowptr[d] + pos;
    csrc[slot] = srcA[e];
    cef[slot * 3 + 0] = ef[e * 3 + 0];
    cef[slot * 3 + 1] = ef[e * 3 + 1];
    cef[slot * 3 + 2] = ef[e * 3 + 2];
}

__global__ void k_selfloop(const int* __restrict__ rowptr, const int* __restrict__ cnt,
                           const float* __restrict__ lsum,
                           int* __restrict__ csrc, float* __restrict__ cef, int N) {
    int i = blockIdx.x * blockDim.x + threadIdx.x;
    if (i >= N) return;
    int slot = rowptr[i] + cnt[i];  // self-loop in last slot of the row
    csrc[slot] = i;
    cef[slot * 3 + 0] = lsum[i * 3 + 0];
    cef[slot * 3 + 1] = lsum[i * 3 + 1];
    cef[slot * 3 + 2] = lsum[i * 3 + 2];
}

// ---------------- node linear transforms: tiled GEMM ----------------
// out = [xin@Wl+bl (as fp16) | xin@Wr+br (as fp32)], register-tiled.
// Block: 32 nodes x OW(=2*HC) outputs, 256 threads.
// Thread: 4 nodes x OPT outputs (OPT = OW/32 = HC/16).
template <int F, int HC>
__global__ void k_lin_t(const float* __restrict__ xin,
                        const float* __restrict__ wl, const float* __restrict__ bl,
                        const float* __restrict__ wr, const float* __restrict__ br,
                        __half* __restrict__ xl16, float* __restrict__ xr, int N) {
    constexpr int OPT = HC / 16;  // outputs per thread (4 or 8)
    __shared__ float xs[32][F + 1];
    int n0 = blockIdx.x * 32;
    int tid = threadIdx.x;

    // stage x tile (coalesced along k)
    for (int idx = tid; idx < 32 * F; idx += TPB) {
        int n = idx / F, k = idx - n * F;
        int gn = n0 + n;
        xs[n][k] = (gn < N) ? xin[(size_t)gn * F + k] : 0.f;
    }
    __syncthreads();

    int og = tid & 31;       // output group
    int ng = tid >> 5;       // node group (0..7)
    int o0 = og * OPT;
    bool isL = o0 < HC;
    int col = isL ? o0 : o0 - HC;
    const float* wp = isL ? wl : wr;
    const float* bp = isL ? bl : br;

    float acc[4][OPT];
    #pragma unroll
    for (int j = 0; j < 4; ++j)
        #pragma unroll
        for (int m = 0; m < OPT; ++m) acc[j][m] = 0.f;

    #pragma unroll 4
    for (int k = 0; k < F; ++k) {
        float wv[OPT];
        #pragma unroll
        for (int m = 0; m < OPT; m += 4)
            *reinterpret_cast<float4*>(&wv[m]) =
                *reinterpret_cast<const float4*>(wp + (size_t)k * HC + col + m);
        #pragma unroll
        for (int j = 0; j < 4; ++j) {
            float xv = xs[ng * 4 + j][k];
            #pragma unroll
            for (int m = 0; m < OPT; ++m) acc[j][m] = fmaf(xv, wv[m], acc[j][m]);
        }
    }

    float bias[OPT];
    #pragma unroll
    for (int m = 0; m < OPT; ++m) bias[m] = bp[col + m];

    #pragma unroll
    for (int j = 0; j < 4; ++j) {
        int node = n0 + ng * 4 + j;
        if (node >= N) continue;
        if (isL) {
            #pragma unroll
            for (int m = 0; m < OPT; m += 2) {
                __half2 hv = __half2(__float2half(acc[j][m] + bias[m]),
                                     __float2half(acc[j][m + 1] + bias[m + 1]));
                *reinterpret_cast<__half2*>(xl16 + (size_t)node * HC + col + m) = hv;
            }
        } else {
            #pragma unroll
            for (int m = 0; m < OPT; m += 4) {
                float4 fv = make_float4(acc[j][m] + bias[m], acc[j][m + 1] + bias[m + 1],
                                        acc[j][m + 2] + bias[m + 2], acc[j][m + 3] + bias[m + 3]);
                *reinterpret_cast<float4*>(xr + (size_t)node * HC + col + m) = fv;
            }
        }
    }
}

// ---------------- fused GATv2 attention + aggregation ----------------
// Per dst node, online-softmax over its CSR row, aggregate in regs.
// One wave handles NPW nodes; each node gets PAIRS=HC/2 lanes (channels 2p,2p+1).
template <int H, int C>
__global__ void k_fused(const int* __restrict__ rowptr, const int* __restrict__ csrc,
                        const float* __restrict__ cef,
                        const __half* __restrict__ xl16, const float* __restrict__ xr,
                        const float* __restrict__ we, const float* __restrict__ att,
                        const float* __restrict__ cb, float* __restrict__ hout, int N) {
    constexpr int HC = H * C;
    constexpr int PAIRS = HC / 2;   // lanes per node
    constexpr int NPW = 64 / PAIRS; // nodes per wave
    int wave = (blockIdx.x * blockDim.x + threadIdx.x) >> 6;
    int lane = threadIdx.x & 63;
    int g = lane / PAIRS;
    int p = lane % PAIRS;
    int node = wave * NPW + g;
    bool act = node < N;

    int o0 = 2 * p, o1 = 2 * p + 1;
    float xr0 = 0.f, xr1 = 0.f;
    int b = 0, len = 0;
    if (act) {
        xr0 = xr[(size_t)node * HC + o0];
        xr1 = xr[(size_t)node * HC + o1];
        b = rowptr[node];
        len = rowptr[node + 1] - b;
    }
    float w0a = we[o0], w0b = we[HC + o0], w0c = we[2 * HC + o0];
    float w1a = we[o1], w1b = we[HC + o1], w1c = we[2 * HC + o1];
    float at0 = att[o0], at1 = att[o1];

    float m_run = -1e30f, den = 0.f, acc0 = 0.f, acc1 = 0.f;

    for (int k = 0; k < len; ++k) {
        int s = b + k;
        int src = csrc[s];
        float f0 = cef[s * 3 + 0], f1 = cef[s * 3 + 1], f2 = cef[s * 3 + 2];
        __half2 hv = *(reinterpret_cast<const __half2*>(xl16 + (size_t)src * HC) + p);
        float2 xv = __half22float2(hv);
        float s0 = xv.x + xr0 + f0 * w0a + f1 * w0b + f2 * w0c;
        float s1 = xv.y + xr1 + f0 * w1a + f1 * w1b + f2 * w1c;
        s0 = (s0 > 0.f) ? s0 : 0.2f * s0;
        s1 = (s1 > 0.f) ? s1 : 0.2f * s1;
        float partial = at0 * s0 + at1 * s1;
        #pragma unroll
        for (int mk = 1; mk < C / 2; mk <<= 1) partial += __shfl_xor(partial, mk);
        float L = partial;  // logit, replicated across the head's C/2 lanes
        float nm = fmaxf(m_run, L);
        float sc = __expf(m_run - nm);
        float pe = __expf(L - nm);
        den = den * sc + pe;
        acc0 = acc0 * sc + pe * xv.x;
        acc1 = acc1 * sc + pe * xv.y;
        m_run = nm;
    }

    if (act) {
        float inv = 1.0f / den;  // every node has a self-loop -> den > 0
        float r0 = fmaxf(acc0 * inv + cb[o0], 0.f);
        float r1 = fmaxf(acc1 * inv + cb[o1], 0.f);
        *reinterpret_cast<float2*>(hout + (size_t)node * HC + o0) = make_float2(r0, r1);
    }
}

// ---------------- pooling + final linear ----------------

__global__ void k_pool(const float* __restrict__ h, const int* __restrict__ batch,
                       float* __restrict__ psum, int* __restrict__ pcnt, int N) {
    int t = blockIdx.x * blockDim.x + threadIdx.x;
    if (t >= N * 64) return;
    int i = t >> 6, o = t & 63;
    int g = batch[i];
    atomicAdd(&psum[g * 64 + o], h[t]);
    if (o == 0) atomicAdd(&pcnt[g], 1);
}

__global__ void k_final(const float* __restrict__ psum, const int* __restrict__ pcnt,
                        const float* __restrict__ wlin, const float* __restrict__ blin,
                        float* __restrict__ out, int G) {
    int t = blockIdx.x * blockDim.x + threadIdx.x;
    if (t >= G * 32) return;
    int g = t / 32, j = t % 32;
    float acc = 0.f;
    for (int k = 0; k < 64; ++k) acc = fmaf(psum[g * 64 + k], wlin[k * 32 + j], acc);
    float inv = 1.0f / (float)max(pcnt[g], 1);
    out[t] = acc * inv + blin[j];
}

// ---------------- host ----------------

extern "C" void kernel_launch(void* const* d_in, const int* in_sizes, int n_in,
                              void* d_out, int out_size, void* d_ws, size_t ws_size,
                              hipStream_t stream) {
    const float* x = (const float*)d_in[0];
    const int* ei = (const int*)d_in[1];
    const float* ef = (const float*)d_in[2];
    const int* batch = (const int*)d_in[3];

    int N = in_sizes[0] / 5;
    int E = in_sizes[1] / 2;
    int G = out_size / 32;
    int Etot = E + N;
    const int* srcA = ei;
    const int* dstA = ei + E;

    char* w = (char*)d_ws;
    size_t off = 0;
    auto A = [&](size_t bytes) -> void* {
        void* p = w + off;
        off = (off + bytes + 255) & ~(size_t)255;
        return p;
    };
    // zero-init region: cnt0, fill, lsum, psum, pcnt
    int* cnt0 = (int*)A((size_t)N * 4);
    int* fill = (int*)A((size_t)N * 4);
    float* lsum = (float*)A((size_t)N * 3 * 4);
    float* psum = (float*)A((size_t)G * 64 * 4);
    int* pcnt = (int*)A((size_t)G * 4);
    size_t zbytes = off;
    int* rowptr = (int*)A((size_t)(N + 1) * 4);
    int* csrc = (int*)A((size_t)Etot * 4);
    float* cef = (float*)A((size_t)Etot * 3 * 4);
    __half* xl16 = (__half*)A((size_t)N * 128 * 2);
    float* xr = (float*)A((size_t)N * 128 * 4);
    float* h0 = (float*)A((size_t)N * 128 * 4);
    float* h1 = (float*)A((size_t)N * 128 * 4);

    hipMemsetAsync(d_ws, 0, zbytes, stream);

    dim3 B(TPB);
    k_count<<<(E + TPB - 1) / TPB, B, 0, stream>>>(dstA, ef, cnt0, lsum, E);
    k_loopdiv<<<(N + TPB - 1) / TPB, B, 0, stream>>>(lsum, cnt0, N);
    k_scan<<<1, B, 0, stream>>>(cnt0, rowptr, N);
    k_fill<<<(E + TPB - 1) / TPB, B, 0, stream>>>(srcA, dstA, ef, rowptr, fill, csrc, cef, E);
    k_selfloop<<<(N + TPB - 1) / TPB, B, 0, stream>>>(rowptr, cnt0, lsum, csrc, cef, N);

    const int Hs[4] = {4, 4, 4, 2};
    const int Cs[4] = {16, 32, 32, 32};
    float* houts[4] = {h0, h1, h0, h1};

    int nblk = (N + 31) / 32;
    const float* hin = x;
    for (int l = 0; l < 4; ++l) {
        const float* wl  = (const float*)d_in[4 + l * 7 + 0];
        const float* bl  = (const float*)d_in[4 + l * 7 + 1];
        const float* wr  = (const float*)d_in[4 + l * 7 + 2];
        const float* br  = (const float*)d_in[4 + l * 7 + 3];
        const float* we  = (const float*)d_in[4 + l * 7 + 4];
        const float* att = (const float*)d_in[4 + l * 7 + 5];
        const float* cb  = (const float*)d_in[4 + l * 7 + 6];
        int H = Hs[l], C = Cs[l], HC = H * C;

        if (l == 0)      k_lin_t<5, 64>  <<<nblk, B, 0, stream>>>(hin, wl, bl, wr, br, xl16, xr, N);
        else if (l == 1) k_lin_t<64, 128><<<nblk, B, 0, stream>>>(hin, wl, bl, wr, br, xl16, xr, N);
        else if (l == 2) k_lin_t<128, 128><<<nblk, B, 0, stream>>>(hin, wl, bl, wr, br, xl16, xr, N);
        else             k_lin_t<128, 64><<<nblk, B, 0, stream>>>(hin, wl, bl, wr, br, xl16, xr, N);

        int npw = 64 / (HC / 2);
        int waves = (N + npw - 1) / npw;
        int blocks = (waves + 3) / 4;  // 4 waves per 256-thread block
        if (H == 4 && C == 16)
            k_fused<4, 16><<<blocks, B, 0, stream>>>(rowptr, csrc, cef, xl16, xr,
                                                     we, att, cb, houts[l], N);
        else if (H == 4 && C == 32)
            k_fused<4, 32><<<blocks, B, 0, stream>>>(rowptr, csrc, cef, xl16, xr,
                                                     we, att, cb, houts[l], N);
        else
            k_fused<2, 32><<<blocks, B, 0, stream>>>(rowptr, csrc, cef, xl16, xr,
                                                     we, att, cb, houts[l], N);
        hin = houts[l];
    }

    k_pool<<<((long long)N * 64 + TPB - 1) / TPB, B, 0, stream>>>(hin, batch, psum, pcnt, N);
    k_final<<<(G * 32 + TPB - 1) / TPB, B, 0, stream>>>(psum, pcnt,
                                                        (const float*)d_in[32],
                                                        (const float*)d_in[33],
                                                        (float*)d_out, G);
}

// Round 4
// 850.507 us; speedup vs baseline: 3.7844x; 1.3237x over previous
//
#include <hip/hip_runtime.h>
#include <hip/hip_fp16.h>

#define TPB 256
#define SCAN_T 1024

// ---------------- CSR build ----------------

__global__ void k_count(const int* __restrict__ dstA, int* __restrict__ cnt, int E) {
    int e = blockIdx.x * blockDim.x + threadIdx.x;
    if (e >= E) return;
    atomicAdd(&cnt[dstA[e]], 1);
}

// exclusive scan of (cnt[i]+1) over N elements, single block
__global__ void k_scan(const int* __restrict__ cnt, int* __restrict__ rowptr, int N) {
    __shared__ int part[SCAN_T];
    __shared__ int offs[SCAN_T];
    int tid = threadIdx.x;
    int chunk = (N + SCAN_T - 1) / SCAN_T;
    int beg = tid * chunk;
    int end = min(beg + chunk, N);
    int s = 0;
    for (int i = beg; i < end; ++i) s += cnt[i] + 1;
    part[tid] = s;
    __syncthreads();
    if (tid == 0) {
        int acc = 0;
        for (int i = 0; i < SCAN_T; ++i) { offs[i] = acc; acc += part[i]; }
    }
    __syncthreads();
    int acc = offs[tid];
    for (int i = beg; i < end; ++i) { rowptr[i] = acc; acc += cnt[i] + 1; }
    if (end == N) rowptr[N] = acc;
}

__global__ void k_fill(const int* __restrict__ srcA, const int* __restrict__ dstA,
                       const float* __restrict__ ef,
                       const int* __restrict__ rowptr, int* __restrict__ fill,
                       int* __restrict__ csrc, float* __restrict__ cef, int E) {
    int e = blockIdx.x * blockDim.x + threadIdx.x;
    if (e >= E) return;
    int d = dstA[e];
    int pos = atomicAdd(&fill[d], 1);
    int slot = rowptr[d] + pos;
    csrc[slot] = srcA[e];
    cef[slot * 3 + 0] = ef[e * 3 + 0];
    cef[slot * 3 + 1] = ef[e * 3 + 1];
    cef[slot * 3 + 2] = ef[e * 3 + 2];
}

// self-loop: mean of the row's edge features, written into the row's last slot
__global__ void k_selfloop(const int* __restrict__ rowptr, const int* __restrict__ cnt,
                           int* __restrict__ csrc, float* __restrict__ cef, int N) {
    int i = blockIdx.x * blockDim.x + threadIdx.x;
    if (i >= N) return;
    int b = rowptr[i];
    int c = cnt[i];
    float s0 = 0.f, s1 = 0.f, s2 = 0.f;
    for (int s = b; s < b + c; ++s) {
        s0 += cef[s * 3 + 0];
        s1 += cef[s * 3 + 1];
        s2 += cef[s * 3 + 2];
    }
    float inv = 1.0f / (float)max(c, 1);
    int slot = b + c;
    csrc[slot] = i;
    cef[slot * 3 + 0] = s0 * inv;
    cef[slot * 3 + 1] = s1 * inv;
    cef[slot * 3 + 2] = s2 * inv;
}

// ---------------- node linear transforms: tiled GEMM ----------------
// out = [xin@Wl+bl (as fp16) | xin@Wr+br (as fp32)], register-tiled.
// Block: 32 nodes x OW(=2*HC) outputs, 256 threads.
// Thread: 4 nodes x OPT outputs (OPT = OW/32 = HC/16).
template <int F, int HC>
__global__ void k_lin_t(const float* __restrict__ xin,
                        const float* __restrict__ wl, const float* __restrict__ bl,
                        const float* __restrict__ wr, const float* __restrict__ br,
                        __half* __restrict__ xl16, float* __restrict__ xr, int N) {
    constexpr int OPT = HC / 16;  // outputs per thread (4 or 8)
    __shared__ float xs[32][F + 1];
    int n0 = blockIdx.x * 32;
    int tid = threadIdx.x;

    for (int idx = tid; idx < 32 * F; idx += TPB) {
        int n = idx / F, k = idx - n * F;
        int gn = n0 + n;
        xs[n][k] = (gn < N) ? xin[(size_t)gn * F + k] : 0.f;
    }
    __syncthreads();

    int og = tid & 31;       // output group
    int ng = tid >> 5;       // node group (0..7)
    int o0 = og * OPT;
    bool isL = o0 < HC;
    int col = isL ? o0 : o0 - HC;
    const float* wp = isL ? wl : wr;
    const float* bp = isL ? bl : br;

    float acc[4][OPT];
    #pragma unroll
    for (int j = 0; j < 4; ++j)
        #pragma unroll
        for (int m = 0; m < OPT; ++m) acc[j][m] = 0.f;

    #pragma unroll 4
    for (int k = 0; k < F; ++k) {
        float wv[OPT];
        #pragma unroll
        for (int m = 0; m < OPT; m += 4)
            *reinterpret_cast<float4*>(&wv[m]) =
                *reinterpret_cast<const float4*>(wp + (size_t)k * HC + col + m);
        #pragma unroll
        for (int j = 0; j < 4; ++j) {
            float xv = xs[ng * 4 + j][k];
            #pragma unroll
            for (int m = 0; m < OPT; ++m) acc[j][m] = fmaf(xv, wv[m], acc[j][m]);
        }
    }

    float bias[OPT];
    #pragma unroll
    for (int m = 0; m < OPT; ++m) bias[m] = bp[col + m];

    #pragma unroll
    for (int j = 0; j < 4; ++j) {
        int node = n0 + ng * 4 + j;
        if (node >= N) continue;
        if (isL) {
            #pragma unroll
            for (int m = 0; m < OPT; m += 2) {
                __half2 hv = __half2(__float2half(acc[j][m] + bias[m]),
                                     __float2half(acc[j][m + 1] + bias[m + 1]));
                *reinterpret_cast<__half2*>(xl16 + (size_t)node * HC + col + m) = hv;
            }
        } else {
            #pragma unroll
            for (int m = 0; m < OPT; m += 4) {
                float4 fv = make_float4(acc[j][m] + bias[m], acc[j][m + 1] + bias[m + 1],
                                        acc[j][m + 2] + bias[m + 2], acc[j][m + 3] + bias[m + 3]);
                *reinterpret_cast<float4*>(xr + (size_t)node * HC + col + m) = fv;
            }
        }
    }
}

// ---------------- fused GATv2 attention + aggregation ----------------
// Per dst node, online-softmax over its CSR row, aggregate in regs.
// One wave handles NPW nodes; each node gets PAIRS=HC/2 lanes (channels 2p,2p+1).
template <int H, int C>
__global__ void k_fused(const int* __restrict__ rowptr, const int* __restrict__ csrc,
                        const float* __restrict__ cef,
                        const __half* __restrict__ xl16, const float* __restrict__ xr,
                        const float* __restrict__ we, const float* __restrict__ att,
                        const float* __restrict__ cb, float* __restrict__ hout, int N) {
    constexpr int HC = H * C;
    constexpr int PAIRS = HC / 2;   // lanes per node
    constexpr int NPW = 64 / PAIRS; // nodes per wave
    int wave = (blockIdx.x * blockDim.x + threadIdx.x) >> 6;
    int lane = threadIdx.x & 63;
    int g = lane / PAIRS;
    int p = lane % PAIRS;
    int node = wave * NPW + g;
    bool act = node < N;

    int o0 = 2 * p, o1 = 2 * p + 1;
    float xr0 = 0.f, xr1 = 0.f;
    int b = 0, len = 0;
    if (act) {
        xr0 = xr[(size_t)node * HC + o0];
        xr1 = xr[(size_t)node * HC + o1];
        b = rowptr[node];
        len = rowptr[node + 1] - b;
    }
    float w0a = we[o0], w0b = we[HC + o0], w0c = we[2 * HC + o0];
    float w1a = we[o1], w1b = we[HC + o1], w1c = we[2 * HC + o1];
    float at0 = att[o0], at1 = att[o1];

    float m_run = -1e30f, den = 0.f, acc0 = 0.f, acc1 = 0.f;

    for (int k = 0; k < len; ++k) {
        int s = b + k;
        int src = csrc[s];
        float f0 = cef[s * 3 + 0], f1 = cef[s * 3 + 1], f2 = cef[s * 3 + 2];
        __half2 hv = *(reinterpret_cast<const __half2*>(xl16 + (size_t)src * HC) + p);
        float2 xv = __half22float2(hv);
        float s0 = xv.x + xr0 + f0 * w0a + f1 * w0b + f2 * w0c;
        float s1 = xv.y + xr1 + f0 * w1a + f1 * w1b + f2 * w1c;
        s0 = (s0 > 0.f) ? s0 : 0.2f * s0;
        s1 = (s1 > 0.f) ? s1 : 0.2f * s1;
        float partial = at0 * s0 + at1 * s1;
        #pragma unroll
        for (int mk = 1; mk < C / 2; mk <<= 1) partial += __shfl_xor(partial, mk);
        float L = partial;  // logit, replicated across the head's C/2 lanes
        float nm = fmaxf(m_run, L);
        float sc = __expf(m_run - nm);
        float pe = __expf(L - nm);
        den = den * sc + pe;
        acc0 = acc0 * sc + pe * xv.x;
        acc1 = acc1 * sc + pe * xv.y;
        m_run = nm;
    }

    if (act) {
        float inv = 1.0f / den;  // every node has a self-loop -> den > 0
        float r0 = fmaxf(acc0 * inv + cb[o0], 0.f);
        float r1 = fmaxf(acc1 * inv + cb[o1], 0.f);
        *reinterpret_cast<float2*>(hout + (size_t)node * HC + o0) = make_float2(r0, r1);
    }
}

// ---------------- pooling + final linear ----------------
// batch is sorted: accumulate runs in registers, one atomic per (run, channel).
__global__ void k_pool(const float* __restrict__ h, const int* __restrict__ batch,
                       float* __restrict__ psum, int* __restrict__ pcnt, int N) {
    int o = threadIdx.x & 63;
    int j = threadIdx.x >> 6;  // 0..3
    int nb = blockIdx.x * 32;
    float acc = 0.f;
    int gcur = -1, cntacc = 0;
    for (int jj = j; jj < 32; jj += 4) {
        int node = nb + jj;
        if (node >= N) break;
        int g = batch[node];
        if (g != gcur) {
            if (gcur >= 0) {
                atomicAdd(&psum[gcur * 64 + o], acc);
                if (o == 0) atomicAdd(&pcnt[gcur], cntacc);
            }
            gcur = g; acc = 0.f; cntacc = 0;
        }
        acc += h[(size_t)node * 64 + o];
        ++cntacc;
    }
    if (gcur >= 0) {
        atomicAdd(&psum[gcur * 64 + o], acc);
        if (o == 0) atomicAdd(&pcnt[gcur], cntacc);
    }
}

__global__ void k_final(const float* __restrict__ psum, const int* __restrict__ pcnt,
                        const float* __restrict__ wlin, const float* __restrict__ blin,
                        float* __restrict__ out, int G) {
    int t = blockIdx.x * blockDim.x + threadIdx.x;
    if (t >= G * 32) return;
    int g = t / 32, j = t % 32;
    float acc = 0.f;
    for (int k = 0; k < 64; ++k) acc = fmaf(psum[g * 64 + k], wlin[k * 32 + j], acc);
    float inv = 1.0f / (float)max(pcnt[g], 1);
    out[t] = acc * inv + blin[j];
}

// ---------------- host ----------------

extern "C" void kernel_launch(void* const* d_in, const int* in_sizes, int n_in,
                              void* d_out, int out_size, void* d_ws, size_t ws_size,
                              hipStream_t stream) {
    const float* x = (const float*)d_in[0];
    const int* ei = (const int*)d_in[1];
    const float* ef = (const float*)d_in[2];
    const int* batch = (const int*)d_in[3];

    int N = in_sizes[0] / 5;
    int E = in_sizes[1] / 2;
    int G = out_size / 32;
    int Etot = E + N;
    const int* srcA = ei;
    const int* dstA = ei + E;

    char* w = (char*)d_ws;
    size_t off = 0;
    auto A = [&](size_t bytes) -> void* {
        void* p = w + off;
        off = (off + bytes + 255) & ~(size_t)255;
        return p;
    };
    // zero-init region: cnt0, fill, psum, pcnt
    int* cnt0 = (int*)A((size_t)N * 4);
    int* fill = (int*)A((size_t)N * 4);
    float* psum = (float*)A((size_t)G * 64 * 4);
    int* pcnt = (int*)A((size_t)G * 4);
    size_t zbytes = off;
    int* rowptr = (int*)A((size_t)(N + 1) * 4);
    int* csrc = (int*)A((size_t)Etot * 4);
    float* cef = (float*)A((size_t)Etot * 3 * 4);
    __half* xl16 = (__half*)A((size_t)N * 128 * 2);
    float* xr = (float*)A((size_t)N * 128 * 4);
    float* h0 = (float*)A((size_t)N * 128 * 4);
    float* h1 = (float*)A((size_t)N * 128 * 4);

    hipMemsetAsync(d_ws, 0, zbytes, stream);

    dim3 B(TPB);
    k_count<<<(E + TPB - 1) / TPB, B, 0, stream>>>(dstA, cnt0, E);
    k_scan<<<1, SCAN_T, 0, stream>>>(cnt0, rowptr, N);
    k_fill<<<(E + TPB - 1) / TPB, B, 0, stream>>>(srcA, dstA, ef, rowptr, fill, csrc, cef, E);
    k_selfloop<<<(N + TPB - 1) / TPB, B, 0, stream>>>(rowptr, cnt0, csrc, cef, N);

    const int Hs[4] = {4, 4, 4, 2};
    const int Cs[4] = {32, 32, 32, 32};  // Cs[0] is 16; fixed below in dispatch
    float* houts[4] = {h0, h1, h0, h1};

    int nblk = (N + 31) / 32;
    const float* hin = x;
    for (int l = 0; l < 4; ++l) {
        const float* wl  = (const float*)d_in[4 + l * 7 + 0];
        const float* bl  = (const float*)d_in[4 + l * 7 + 1];
        const float* wr  = (const float*)d_in[4 + l * 7 + 2];
        const float* br  = (const float*)d_in[4 + l * 7 + 3];
        const float* we  = (const float*)d_in[4 + l * 7 + 4];
        const float* att = (const float*)d_in[4 + l * 7 + 5];
        const float* cb  = (const float*)d_in[4 + l * 7 + 6];
        int H = (l == 3) ? 2 : 4;
        int C = (l == 0) ? 16 : 32;
        int HC = H * C;

        if (l == 0)      k_lin_t<5, 64>   <<<nblk, B, 0, stream>>>(hin, wl, bl, wr, br, xl16, xr, N);
        else if (l == 1) k_lin_t<64, 128> <<<nblk, B, 0, stream>>>(hin, wl, bl, wr, br, xl16, xr, N);
        else if (l == 2) k_lin_t<128, 128><<<nblk, B, 0, stream>>>(hin, wl, bl, wr, br, xl16, xr, N);
        else             k_lin_t<128, 64> <<<nblk, B, 0, stream>>>(hin, wl, bl, wr, br, xl16, xr, N);

        int npw = 64 / (HC / 2);
        int waves = (N + npw - 1) / npw;
        int blocks = (waves + 3) / 4;  // 4 waves per 256-thread block
        if (H == 4 && C == 16)
            k_fused<4, 16><<<blocks, B, 0, stream>>>(rowptr, csrc, cef, xl16, xr,
                                                     we, att, cb, houts[l], N);
        else if (H == 4 && C == 32)
            k_fused<4, 32><<<blocks, B, 0, stream>>>(rowptr, csrc, cef, xl16, xr,
                                                     we, att, cb, houts[l], N);
        else
            k_fused<2, 32><<<blocks, B, 0, stream>>>(rowptr, csrc, cef, xl16, xr,
                                                     we, att, cb, houts[l], N);
        hin = houts[l];
    }

    k_pool<<<(N + 31) / 32, B, 0, stream>>>(hin, batch, psum, pcnt, N);
    k_final<<<(G * 32 + TPB - 1) / TPB, B, 0, stream>>>(psum, pcnt,
                                                        (const float*)d_in[32],
                                                        (const float*)d_in[33],
                                                        (float*)d_out, G);
}

// Round 5
// 683.797 us; speedup vs baseline: 4.7070x; 1.2438x over previous
//
#include <hip/hip_runtime.h>
#include <hip/hip_fp16.h>

#define TPB 256
#define SCAN_T 1024

// ---------------- CSR build ----------------

__global__ void k_count(const int* __restrict__ dstA, int* __restrict__ cnt, int E) {
    int e = blockIdx.x * blockDim.x + threadIdx.x;
    if (e >= E) return;
    atomicAdd(&cnt[dstA[e]], 1);
}

// exclusive scan of (cnt[i]+1) over N elements, single block
__global__ void k_scan(const int* __restrict__ cnt, int* __restrict__ rowptr, int N) {
    __shared__ int part[SCAN_T];
    __shared__ int offs[SCAN_T];
    int tid = threadIdx.x;
    int chunk = (N + SCAN_T - 1) / SCAN_T;
    int beg = tid * chunk;
    int end = min(beg + chunk, N);
    int s = 0;
    for (int i = beg; i < end; ++i) s += cnt[i] + 1;
    part[tid] = s;
    __syncthreads();
    if (tid == 0) {
        int acc = 0;
        for (int i = 0; i < SCAN_T; ++i) { offs[i] = acc; acc += part[i]; }
    }
    __syncthreads();
    int acc = offs[tid];
    for (int i = beg; i < end; ++i) { rowptr[i] = acc; acc += cnt[i] + 1; }
    if (end == N) rowptr[N] = acc;
}

__global__ void k_fill(const int* __restrict__ srcA, const int* __restrict__ dstA,
                       const float* __restrict__ ef,
                       const int* __restrict__ rowptr, int* __restrict__ fill,
                       int* __restrict__ csrc, float* __restrict__ cef, int E) {
    int e = blockIdx.x * blockDim.x + threadIdx.x;
    if (e >= E) return;
    int d = dstA[e];
    int pos = atomicAdd(&fill[d], 1);
    int slot = rowptr[d] + pos;
    csrc[slot] = srcA[e];
    cef[slot * 3 + 0] = ef[e * 3 + 0];
    cef[slot * 3 + 1] = ef[e * 3 + 1];
    cef[slot * 3 + 2] = ef[e * 3 + 2];
}

// self-loop: mean of the row's edge features, written into the row's last slot
__global__ void k_selfloop(const int* __restrict__ rowptr, const int* __restrict__ cnt,
                           int* __restrict__ csrc, float* __restrict__ cef, int N) {
    int i = blockIdx.x * blockDim.x + threadIdx.x;
    if (i >= N) return;
    int b = rowptr[i];
    int c = cnt[i];
    float s0 = 0.f, s1 = 0.f, s2 = 0.f;
    for (int s = b; s < b + c; ++s) {
        s0 += cef[s * 3 + 0];
        s1 += cef[s * 3 + 1];
        s2 += cef[s * 3 + 2];
    }
    float inv = 1.0f / (float)max(c, 1);
    int slot = b + c;
    csrc[slot] = i;
    cef[slot * 3 + 0] = s0 * inv;
    cef[slot * 3 + 1] = s1 * inv;
    cef[slot * 3 + 2] = s2 * inv;
}

// ---------------- node linear transforms: tiled GEMM ----------------
template <int F, int HC>
__global__ void k_lin_t(const float* __restrict__ xin,
                        const float* __restrict__ wl, const float* __restrict__ bl,
                        const float* __restrict__ wr, const float* __restrict__ br,
                        __half* __restrict__ xl16, float* __restrict__ xr, int N) {
    constexpr int OPT = HC / 16;  // outputs per thread (4 or 8)
    __shared__ float xs[32][F + 1];
    int n0 = blockIdx.x * 32;
    int tid = threadIdx.x;

    for (int idx = tid; idx < 32 * F; idx += TPB) {
        int n = idx / F, k = idx - n * F;
        int gn = n0 + n;
        xs[n][k] = (gn < N) ? xin[(size_t)gn * F + k] : 0.f;
    }
    __syncthreads();

    int og = tid & 31;       // output group
    int ng = tid >> 5;       // node group (0..7)
    int o0 = og * OPT;
    bool isL = o0 < HC;
    int col = isL ? o0 : o0 - HC;
    const float* wp = isL ? wl : wr;
    const float* bp = isL ? bl : br;

    float acc[4][OPT];
    #pragma unroll
    for (int j = 0; j < 4; ++j)
        #pragma unroll
        for (int m = 0; m < OPT; ++m) acc[j][m] = 0.f;

    #pragma unroll 4
    for (int k = 0; k < F; ++k) {
        float wv[OPT];
        #pragma unroll
        for (int m = 0; m < OPT; m += 4)
            *reinterpret_cast<float4*>(&wv[m]) =
                *reinterpret_cast<const float4*>(wp + (size_t)k * HC + col + m);
        #pragma unroll
        for (int j = 0; j < 4; ++j) {
            float xv = xs[ng * 4 + j][k];
            #pragma unroll
            for (int m = 0; m < OPT; ++m) acc[j][m] = fmaf(xv, wv[m], acc[j][m]);
        }
    }

    float bias[OPT];
    #pragma unroll
    for (int m = 0; m < OPT; ++m) bias[m] = bp[col + m];

    #pragma unroll
    for (int j = 0; j < 4; ++j) {
        int node = n0 + ng * 4 + j;
        if (node >= N) continue;
        if (isL) {
            #pragma unroll
            for (int m = 0; m < OPT; m += 2) {
                __half2 hv = __half2(__float2half(acc[j][m] + bias[m]),
                                     __float2half(acc[j][m + 1] + bias[m + 1]));
                *reinterpret_cast<__half2*>(xl16 + (size_t)node * HC + col + m) = hv;
            }
        } else {
            #pragma unroll
            for (int m = 0; m < OPT; m += 4) {
                float4 fv = make_float4(acc[j][m] + bias[m], acc[j][m + 1] + bias[m + 1],
                                        acc[j][m + 2] + bias[m + 2], acc[j][m + 3] + bias[m + 3]);
                *reinterpret_cast<float4*>(xr + (size_t)node * HC + col + m) = fv;
            }
        }
    }
}

// ---------------- fused GATv2 attention + aggregation ----------------
// Per dst node, online-softmax over its CSR row, aggregate in regs.
// 4-edge-unrolled: 4 independent gathers in flight, one merged rescale per block.
template <int H, int C>
__global__ void k_fused(const int* __restrict__ rowptr, const int* __restrict__ csrc,
                        const float* __restrict__ cef,
                        const __half* __restrict__ xl16, const float* __restrict__ xr,
                        const float* __restrict__ we, const float* __restrict__ att,
                        const float* __restrict__ cb, float* __restrict__ hout, int N) {
    constexpr int HC = H * C;
    constexpr int PAIRS = HC / 2;   // lanes per node
    constexpr int NPW = 64 / PAIRS; // nodes per wave
    int wave = (blockIdx.x * blockDim.x + threadIdx.x) >> 6;
    int lane = threadIdx.x & 63;
    int g = lane / PAIRS;
    int p = lane % PAIRS;
    int node = wave * NPW + g;
    bool act = node < N;

    int o0 = 2 * p, o1 = 2 * p + 1;
    float xr0 = 0.f, xr1 = 0.f;
    int b = 0, len = 0;
    if (act) {
        xr0 = xr[(size_t)node * HC + o0];
        xr1 = xr[(size_t)node * HC + o1];
        b = rowptr[node];
        len = rowptr[node + 1] - b;
    }
    float w0a = we[o0], w0b = we[HC + o0], w0c = we[2 * HC + o0];
    float w1a = we[o1], w1b = we[HC + o1], w1c = we[2 * HC + o1];
    float at0 = att[o0], at1 = att[o1];

    float m_run = -1e30f, den = 0.f, acc0 = 0.f, acc1 = 0.f;

    int nk = (len + 3) >> 2;
    for (int kb = 0; kb < nk; ++kb) {
        int k0 = kb * 4;
        float L[4];
        float xa[4], xb[4];
        #pragma unroll
        for (int u = 0; u < 4; ++u) {
            int kk = k0 + u;
            bool v = kk < len;
            int s = b + (v ? kk : 0);
            int src = csrc[s];
            float f0 = cef[s * 3 + 0], f1 = cef[s * 3 + 1], f2 = cef[s * 3 + 2];
            __half2 hv = *(reinterpret_cast<const __half2*>(xl16 + (size_t)src * HC) + p);
            float2 x2 = __half22float2(hv);
            float s0 = x2.x + xr0 + f0 * w0a + f1 * w0b + f2 * w0c;
            float s1 = x2.y + xr1 + f0 * w1a + f1 * w1b + f2 * w1c;
            s0 = (s0 > 0.f) ? s0 : 0.2f * s0;
            s1 = (s1 > 0.f) ? s1 : 0.2f * s1;
            float partial = at0 * s0 + at1 * s1;
            #pragma unroll
            for (int mk = 1; mk < C / 2; mk <<= 1) partial += __shfl_xor(partial, mk);
            L[u] = v ? partial : -1e30f;
            xa[u] = x2.x;
            xb[u] = x2.y;
        }
        float Lm = fmaxf(fmaxf(L[0], L[1]), fmaxf(L[2], L[3]));
        float nm = fmaxf(m_run, Lm);
        float sc = __expf(m_run - nm);
        float p0 = __expf(L[0] - nm), p1 = __expf(L[1] - nm);
        float p2 = __expf(L[2] - nm), p3 = __expf(L[3] - nm);
        den = den * sc + ((p0 + p1) + (p2 + p3));
        acc0 = fmaf(acc0, sc, fmaf(p0, xa[0], fmaf(p1, xa[1], fmaf(p2, xa[2], p3 * xa[3]))));
        acc1 = fmaf(acc1, sc, fmaf(p0, xb[0], fmaf(p1, xb[1], fmaf(p2, xb[2], p3 * xb[3]))));
        m_run = nm;
    }

    if (act) {
        float inv = 1.0f / den;  // every node has a self-loop -> den > 0
        float r0 = fmaxf(acc0 * inv + cb[o0], 0.f);
        float r1 = fmaxf(acc1 * inv + cb[o1], 0.f);
        *reinterpret_cast<float2*>(hout + (size_t)node * HC + o0) = make_float2(r0, r1);
    }
}

// ---------------- pooling + final linear ----------------
// batch is sorted: accumulate runs in registers, one atomic per (run, channel).
__global__ void k_pool(const float* __restrict__ h, const int* __restrict__ batch,
                       float* __restrict__ psum, int* __restrict__ pcnt, int N) {
    int o = threadIdx.x & 63;
    int j = threadIdx.x >> 6;  // 0..3
    int nb = blockIdx.x * 32;
    float acc = 0.f;
    int gcur = -1, cntacc = 0;
    for (int jj = j; jj < 32; jj += 4) {
        int node = nb + jj;
        if (node >= N) break;
        int g = batch[node];
        if (g != gcur) {
            if (gcur >= 0) {
                atomicAdd(&psum[gcur * 64 + o], acc);
                if (o == 0) atomicAdd(&pcnt[gcur], cntacc);
            }
            gcur = g; acc = 0.f; cntacc = 0;
        }
        acc += h[(size_t)node * 64 + o];
        ++cntacc;
    }
    if (gcur >= 0) {
        atomicAdd(&psum[gcur * 64 + o], acc);
        if (o == 0) atomicAdd(&pcnt[gcur], cntacc);
    }
}

__global__ void k_final(const float* __restrict__ psum, const int* __restrict__ pcnt,
                        const float* __restrict__ wlin, const float* __restrict__ blin,
                        float* __restrict__ out, int G) {
    int t = blockIdx.x * blockDim.x + threadIdx.x;
    if (t >= G * 32) return;
    int g = t / 32, j = t % 32;
    float acc = 0.f;
    for (int k = 0; k < 64; ++k) acc = fmaf(psum[g * 64 + k], wlin[k * 32 + j], acc);
    float inv = 1.0f / (float)max(pcnt[g], 1);
    out[t] = acc * inv + blin[j];
}

// ---------------- host ----------------

extern "C" void kernel_launch(void* const* d_in, const int* in_sizes, int n_in,
                              void* d_out, int out_size, void* d_ws, size_t ws_size,
                              hipStream_t stream) {
    const float* x = (const float*)d_in[0];
    const int* ei = (const int*)d_in[1];
    const float* ef = (const float*)d_in[2];
    const int* batch = (const int*)d_in[3];

    int N = in_sizes[0] / 5;
    int E = in_sizes[1] / 2;
    int G = out_size / 32;
    int Etot = E + N;
    const int* srcA = ei;
    const int* dstA = ei + E;

    char* w = (char*)d_ws;
    size_t off = 0;
    auto A = [&](size_t bytes) -> void* {
        void* p = w + off;
        off = (off + bytes + 255) & ~(size_t)255;
        return p;
    };
    // zero-init region: cnt0, fill, psum, pcnt
    int* cnt0 = (int*)A((size_t)N * 4);
    int* fill = (int*)A((size_t)N * 4);
    float* psum = (float*)A((size_t)G * 64 * 4);
    int* pcnt = (int*)A((size_t)G * 4);
    size_t zbytes = off;
    int* rowptr = (int*)A((size_t)(N + 1) * 4);
    int* csrc = (int*)A((size_t)Etot * 4);
    float* cef = (float*)A((size_t)Etot * 3 * 4);
    __half* xl16 = (__half*)A((size_t)N * 128 * 2);
    float* xr = (float*)A((size_t)N * 128 * 4);
    float* h0 = (float*)A((size_t)N * 128 * 4);
    float* h1 = (float*)A((size_t)N * 128 * 4);

    hipMemsetAsync(d_ws, 0, zbytes, stream);

    dim3 B(TPB);
    k_count<<<(E + TPB - 1) / TPB, B, 0, stream>>>(dstA, cnt0, E);
    k_scan<<<1, SCAN_T, 0, stream>>>(cnt0, rowptr, N);
    k_fill<<<(E + TPB - 1) / TPB, B, 0, stream>>>(srcA, dstA, ef, rowptr, fill, csrc, cef, E);
    k_selfloop<<<(N + TPB - 1) / TPB, B, 0, stream>>>(rowptr, cnt0, csrc, cef, N);

    float* houts[4] = {h0, h1, h0, h1};

    int nblk = (N + 31) / 32;
    const float* hin = x;
    for (int l = 0; l < 4; ++l) {
        const float* wl  = (const float*)d_in[4 + l * 7 + 0];
        const float* bl  = (const float*)d_in[4 + l * 7 + 1];
        const float* wr  = (const float*)d_in[4 + l * 7 + 2];
        const float* br  = (const float*)d_in[4 + l * 7 + 3];
        const float* we  = (const float*)d_in[4 + l * 7 + 4];
        const float* att = (const float*)d_in[4 + l * 7 + 5];
        const float* cb  = (const float*)d_in[4 + l * 7 + 6];
        int H = (l == 3) ? 2 : 4;
        int C = (l == 0) ? 16 : 32;
        int HC = H * C;

        if (l == 0)      k_lin_t<5, 64>   <<<nblk, B, 0, stream>>>(hin, wl, bl, wr, br, xl16, xr, N);
        else if (l == 1) k_lin_t<64, 128> <<<nblk, B, 0, stream>>>(hin, wl, bl, wr, br, xl16, xr, N);
        else if (l == 2) k_lin_t<128, 128><<<nblk, B, 0, stream>>>(hin, wl, bl, wr, br, xl16, xr, N);
        else             k_lin_t<128, 64> <<<nblk, B, 0, stream>>>(hin, wl, bl, wr, br, xl16, xr, N);

        int npw = 64 / (HC / 2);
        int waves = (N + npw - 1) / npw;
        int blocks = (waves + 3) / 4;  // 4 waves per 256-thread block
        if (H == 4 && C == 16)
            k_fused<4, 16><<<blocks, B, 0, stream>>>(rowptr, csrc, cef, xl16, xr,
                                                     we, att, cb, houts[l], N);
        else if (H == 4 && C == 32)
            k_fused<4, 32><<<blocks, B, 0, stream>>>(rowptr, csrc, cef, xl16, xr,
                                                     we, att, cb, houts[l], N);
        else
            k_fused<2, 32><<<blocks, B, 0, stream>>>(rowptr, csrc, cef, xl16, xr,
                                                     we, att, cb, houts[l], N);
        hin = houts[l];
    }

    k_pool<<<(N + 31) / 32, B, 0, stream>>>(hin, batch, psum, pcnt, N);
    k_final<<<(G * 32 + TPB - 1) / TPB, B, 0, stream>>>(psum, pcnt,
                                                        (const float*)d_in[32],
                                                        (const float*)d_in[33],
                                                        (float*)d_out, G);
}

// Round 6
// 591.139 us; speedup vs baseline: 5.4448x; 1.1567x over previous
//
#include <hip/hip_runtime.h>
#include <hip/hip_fp16.h>

#define TPB 256

// ---------------- CSR build ----------------

__global__ void k_count(const int* __restrict__ dstA, int* __restrict__ cnt, int E) {
    int e = blockIdx.x * blockDim.x + threadIdx.x;
    if (e >= E) return;
    atomicAdd(&cnt[dstA[e]], 1);
}

// ---- 3-phase exclusive scan of (cnt[i]+1) ----
// phase 1: per-block totals
__global__ void k_scan_part(const int* __restrict__ cnt, int* __restrict__ part,
                            int N, int ept) {
    __shared__ int sm[TPB];
    int tid = threadIdx.x;
    int beg = (blockIdx.x * TPB + tid) * ept;
    int s = 0;
    for (int u = 0; u < ept; ++u) {
        int i = beg + u;
        if (i < N) s += cnt[i] + 1;
    }
    sm[tid] = s;
    __syncthreads();
    for (int st = TPB / 2; st; st >>= 1) {
        if (tid < st) sm[tid] += sm[tid + st];
        __syncthreads();
    }
    if (tid == 0) part[blockIdx.x] = sm[0];
}

// phase 2: one wave scans <=64 block partials (exclusive), writes total to rowptr[N]
__global__ void k_scan_top(int* __restrict__ part, int* __restrict__ rowptr,
                           int nb, int N) {
    int lane = threadIdx.x & 63;
    int orig = (lane < nb) ? part[lane] : 0;
    int v = orig;
    #pragma unroll
    for (int ofs = 1; ofs < 64; ofs <<= 1) {
        int t = __shfl_up(v, ofs);
        if (lane >= ofs) v += t;
    }
    if (lane < nb) part[lane] = v - orig;  // exclusive block offset
    if (lane == 63) rowptr[N] = v;         // grand total
}

// phase 3: recompute local sums, block-exclusive-scan, add block offset, emit rowptr
__global__ void k_scan_fin(const int* __restrict__ cnt, const int* __restrict__ part,
                           int* __restrict__ rowptr, int N, int ept) {
    __shared__ int wsum[TPB / 64];
    int tid = threadIdx.x;
    int lane = tid & 63, wid = tid >> 6;
    int beg = (blockIdx.x * TPB + tid) * ept;
    int s = 0;
    for (int u = 0; u < ept; ++u) {
        int i = beg + u;
        if (i < N) s += cnt[i] + 1;
    }
    int v = s;
    #pragma unroll
    for (int ofs = 1; ofs < 64; ofs <<= 1) {
        int t = __shfl_up(v, ofs);
        if (lane >= ofs) v += t;
    }
    if (lane == 63) wsum[wid] = v;
    __syncthreads();
    int woff = 0;
    for (int k = 0; k < wid; ++k) woff += wsum[k];
    int acc = (v - s) + woff + part[blockIdx.x];
    for (int u = 0; u < ept; ++u) {
        int i = beg + u;
        if (i < N) { rowptr[i] = acc; acc += cnt[i] + 1; }
    }
}

__global__ void k_fill(const int* __restrict__ srcA, const int* __restrict__ dstA,
                       const float* __restrict__ ef,
                       const int* __restrict__ rowptr, int* __restrict__ fill,
                       int* __restrict__ csrc, float* __restrict__ cef, int E) {
    int e = blockIdx.x * blockDim.x + threadIdx.x;
    if (e >= E) return;
    int d = dstA[e];
    int pos = atomicAdd(&fill[d], 1);
    int slot = rowptr[d] + pos;
    csrc[slot] = srcA[e];
    cef[slot * 3 + 0] = ef[e * 3 + 0];
    cef[slot * 3 + 1] = ef[e * 3 + 1];
    cef[slot * 3 + 2] = ef[e * 3 + 2];
}

// self-loop: mean of the row's edge features, written into the row's last slot
__global__ void k_selfloop(const int* __restrict__ rowptr, const int* __restrict__ cnt,
                           int* __restrict__ csrc, float* __restrict__ cef, int N) {
    int i = blockIdx.x * blockDim.x + threadIdx.x;
    if (i >= N) return;
    int b = rowptr[i];
    int c = cnt[i];
    float s0 = 0.f, s1 = 0.f, s2 = 0.f;
    for (int s = b; s < b + c; ++s) {
        s0 += cef[s * 3 + 0];
        s1 += cef[s * 3 + 1];
        s2 += cef[s * 3 + 2];
    }
    float inv = 1.0f / (float)max(c, 1);
    int slot = b + c;
    csrc[slot] = i;
    cef[slot * 3 + 0] = s0 * inv;
    cef[slot * 3 + 1] = s1 * inv;
    cef[slot * 3 + 2] = s2 * inv;
}

// ---------------- node linear transforms: tiled GEMM ----------------
template <int F, int HC>
__global__ void k_lin_t(const float* __restrict__ xin,
                        const float* __restrict__ wl, const float* __restrict__ bl,
                        const float* __restrict__ wr, const float* __restrict__ br,
                        __half* __restrict__ xl16, float* __restrict__ xr, int N) {
    constexpr int OPT = HC / 16;  // outputs per thread (4 or 8)
    __shared__ float xs[32][F + 1];
    int n0 = blockIdx.x * 32;
    int tid = threadIdx.x;

    for (int idx = tid; idx < 32 * F; idx += TPB) {
        int n = idx / F, k = idx - n * F;
        int gn = n0 + n;
        xs[n][k] = (gn < N) ? xin[(size_t)gn * F + k] : 0.f;
    }
    __syncthreads();

    int og = tid & 31;       // output group
    int ng = tid >> 5;       // node group (0..7)
    int o0 = og * OPT;
    bool isL = o0 < HC;
    int col = isL ? o0 : o0 - HC;
    const float* wp = isL ? wl : wr;
    const float* bp = isL ? bl : br;

    float acc[4][OPT];
    #pragma unroll
    for (int j = 0; j < 4; ++j)
        #pragma unroll
        for (int m = 0; m < OPT; ++m) acc[j][m] = 0.f;

    #pragma unroll 4
    for (int k = 0; k < F; ++k) {
        float wv[OPT];
        #pragma unroll
        for (int m = 0; m < OPT; m += 4)
            *reinterpret_cast<float4*>(&wv[m]) =
                *reinterpret_cast<const float4*>(wp + (size_t)k * HC + col + m);
        #pragma unroll
        for (int j = 0; j < 4; ++j) {
            float xv = xs[ng * 4 + j][k];
            #pragma unroll
            for (int m = 0; m < OPT; ++m) acc[j][m] = fmaf(xv, wv[m], acc[j][m]);
        }
    }

    float bias[OPT];
    #pragma unroll
    for (int m = 0; m < OPT; ++m) bias[m] = bp[col + m];

    #pragma unroll
    for (int j = 0; j < 4; ++j) {
        int node = n0 + ng * 4 + j;
        if (node >= N) continue;
        if (isL) {
            #pragma unroll
            for (int m = 0; m < OPT; m += 2) {
                __half2 hv = __half2(__float2half(acc[j][m] + bias[m]),
                                     __float2half(acc[j][m + 1] + bias[m + 1]));
                *reinterpret_cast<__half2*>(xl16 + (size_t)node * HC + col + m) = hv;
            }
        } else {
            #pragma unroll
            for (int m = 0; m < OPT; m += 4) {
                float4 fv = make_float4(acc[j][m] + bias[m], acc[j][m + 1] + bias[m + 1],
                                        acc[j][m + 2] + bias[m + 2], acc[j][m + 3] + bias[m + 3]);
                *reinterpret_cast<float4*>(xr + (size_t)node * HC + col + m) = fv;
            }
        }
    }
}

// ---------------- fused GATv2 attention + aggregation ----------------
// Per dst node, online-softmax over its CSR row, aggregate in regs.
// 4-edge-unrolled: 4 independent gathers in flight, one merged rescale per block.
template <int H, int C>
__global__ void k_fused(const int* __restrict__ rowptr, const int* __restrict__ csrc,
                        const float* __restrict__ cef,
                        const __half* __restrict__ xl16, const float* __restrict__ xr,
                        const float* __restrict__ we, const float* __restrict__ att,
                        const float* __restrict__ cb, float* __restrict__ hout, int N) {
    constexpr int HC = H * C;
    constexpr int PAIRS = HC / 2;   // lanes per node
    constexpr int NPW = 64 / PAIRS; // nodes per wave
    int wave = (blockIdx.x * blockDim.x + threadIdx.x) >> 6;
    int lane = threadIdx.x & 63;
    int g = lane / PAIRS;
    int p = lane % PAIRS;
    int node = wave * NPW + g;
    bool act = node < N;

    int o0 = 2 * p, o1 = 2 * p + 1;
    float xr0 = 0.f, xr1 = 0.f;
    int b = 0, len = 0;
    if (act) {
        xr0 = xr[(size_t)node * HC + o0];
        xr1 = xr[(size_t)node * HC + o1];
        b = rowptr[node];
        len = rowptr[node + 1] - b;
    }
    float w0a = we[o0], w0b = we[HC + o0], w0c = we[2 * HC + o0];
    float w1a = we[o1], w1b = we[HC + o1], w1c = we[2 * HC + o1];
    float at0 = att[o0], at1 = att[o1];

    float m_run = -1e30f, den = 0.f, acc0 = 0.f, acc1 = 0.f;

    int nk = (len + 3) >> 2;
    for (int kb = 0; kb < nk; ++kb) {
        int k0 = kb * 4;
        float L[4];
        float xa[4], xb[4];
        #pragma unroll
        for (int u = 0; u < 4; ++u) {
            int kk = k0 + u;
            bool v = kk < len;
            int s = b + (v ? kk : 0);
            int src = csrc[s];
            float f0 = cef[s * 3 + 0], f1 = cef[s * 3 + 1], f2 = cef[s * 3 + 2];
            __half2 hv = *(reinterpret_cast<const __half2*>(xl16 + (size_t)src * HC) + p);
            float2 x2 = __half22float2(hv);
            float s0 = x2.x + xr0 + f0 * w0a + f1 * w0b + f2 * w0c;
            float s1 = x2.y + xr1 + f0 * w1a + f1 * w1b + f2 * w1c;
            s0 = (s0 > 0.f) ? s0 : 0.2f * s0;
            s1 = (s1 > 0.f) ? s1 : 0.2f * s1;
            float partial = at0 * s0 + at1 * s1;
            #pragma unroll
            for (int mk = 1; mk < C / 2; mk <<= 1) partial += __shfl_xor(partial, mk);
            L[u] = v ? partial : -1e30f;
            xa[u] = x2.x;
            xb[u] = x2.y;
        }
        float Lm = fmaxf(fmaxf(L[0], L[1]), fmaxf(L[2], L[3]));
        float nm = fmaxf(m_run, Lm);
        float sc = __expf(m_run - nm);
        float p0 = __expf(L[0] - nm), p1 = __expf(L[1] - nm);
        float p2 = __expf(L[2] - nm), p3 = __expf(L[3] - nm);
        den = den * sc + ((p0 + p1) + (p2 + p3));
        acc0 = fmaf(acc0, sc, fmaf(p0, xa[0], fmaf(p1, xa[1], fmaf(p2, xa[2], p3 * xa[3]))));
        acc1 = fmaf(acc1, sc, fmaf(p0, xb[0], fmaf(p1, xb[1], fmaf(p2, xb[2], p3 * xb[3]))));
        m_run = nm;
    }

    if (act) {
        float inv = 1.0f / den;  // every node has a self-loop -> den > 0
        float r0 = fmaxf(acc0 * inv + cb[o0], 0.f);
        float r1 = fmaxf(acc1 * inv + cb[o1], 0.f);
        *reinterpret_cast<float2*>(hout + (size_t)node * HC + o0) = make_float2(r0, r1);
    }
}

// ---------------- pooling + final linear ----------------
// batch is sorted: accumulate runs in registers, one atomic per (run, channel).
__global__ void k_pool(const float* __restrict__ h, const int* __restrict__ batch,
                       float* __restrict__ psum, int* __restrict__ pcnt, int N) {
    int o = threadIdx.x & 63;
    int j = threadIdx.x >> 6;  // 0..3
    int nb = blockIdx.x * 32;
    float acc = 0.f;
    int gcur = -1, cntacc = 0;
    for (int jj = j; jj < 32; jj += 4) {
        int node = nb + jj;
        if (node >= N) break;
        int g = batch[node];
        if (g != gcur) {
            if (gcur >= 0) {
                atomicAdd(&psum[gcur * 64 + o], acc);
                if (o == 0) atomicAdd(&pcnt[gcur], cntacc);
            }
            gcur = g; acc = 0.f; cntacc = 0;
        }
        acc += h[(size_t)node * 64 + o];
        ++cntacc;
    }
    if (gcur >= 0) {
        atomicAdd(&psum[gcur * 64 + o], acc);
        if (o == 0) atomicAdd(&pcnt[gcur], cntacc);
    }
}

__global__ void k_final(const float* __restrict__ psum, const int* __restrict__ pcnt,
                        const float* __restrict__ wlin, const float* __restrict__ blin,
                        float* __restrict__ out, int G) {
    int t = blockIdx.x * blockDim.x + threadIdx.x;
    if (t >= G * 32) return;
    int g = t / 32, j = t % 32;
    float acc = 0.f;
    for (int k = 0; k < 64; ++k) acc = fmaf(psum[g * 64 + k], wlin[k * 32 + j], acc);
    float inv = 1.0f / (float)max(pcnt[g], 1);
    out[t] = acc * inv + blin[j];
}

// ---------------- host ----------------

extern "C" void kernel_launch(void* const* d_in, const int* in_sizes, int n_in,
                              void* d_out, int out_size, void* d_ws, size_t ws_size,
                              hipStream_t stream) {
    const float* x = (const float*)d_in[0];
    const int* ei = (const int*)d_in[1];
    const float* ef = (const float*)d_in[2];
    const int* batch = (const int*)d_in[3];

    int N = in_sizes[0] / 5;
    int E = in_sizes[1] / 2;
    int G = out_size / 32;
    int Etot = E + N;
    const int* srcA = ei;
    const int* dstA = ei + E;

    char* w = (char*)d_ws;
    size_t off = 0;
    auto A = [&](size_t bytes) -> void* {
        void* p = w + off;
        off = (off + bytes + 255) & ~(size_t)255;
        return p;
    };
    // zero-init region: cnt0, fill, psum, pcnt
    int* cnt0 = (int*)A((size_t)N * 4);
    int* fill = (int*)A((size_t)N * 4);
    float* psum = (float*)A((size_t)G * 64 * 4);
    int* pcnt = (int*)A((size_t)G * 4);
    size_t zbytes = off;
    int* rowptr = (int*)A((size_t)(N + 1) * 4);
    int* part = (int*)A((size_t)64 * 4);
    int* csrc = (int*)A((size_t)Etot * 4);
    float* cef = (float*)A((size_t)Etot * 3 * 4);
    __half* xl16 = (__half*)A((size_t)N * 128 * 2);
    float* xr = (float*)A((size_t)N * 128 * 4);
    float* h0 = (float*)A((size_t)N * 128 * 4);
    float* h1 = (float*)A((size_t)N * 128 * 4);

    hipMemsetAsync(d_ws, 0, zbytes, stream);

    dim3 B(TPB);
    k_count<<<(E + TPB - 1) / TPB, B, 0, stream>>>(dstA, cnt0, E);

    // 3-phase scan: ept elems/thread so that #blocks <= 64
    int ept = (N + 64 * TPB - 1) / (64 * TPB);
    if (ept < 4) ept = 4;
    int nb = (N + ept * TPB - 1) / (ept * TPB);
    k_scan_part<<<nb, B, 0, stream>>>(cnt0, part, N, ept);
    k_scan_top<<<1, 64, 0, stream>>>(part, rowptr, nb, N);
    k_scan_fin<<<nb, B, 0, stream>>>(cnt0, part, rowptr, N, ept);

    k_fill<<<(E + TPB - 1) / TPB, B, 0, stream>>>(srcA, dstA, ef, rowptr, fill, csrc, cef, E);
    k_selfloop<<<(N + TPB - 1) / TPB, B, 0, stream>>>(rowptr, cnt0, csrc, cef, N);

    float* houts[4] = {h0, h1, h0, h1};

    int nblk = (N + 31) / 32;
    const float* hin = x;
    for (int l = 0; l < 4; ++l) {
        const float* wl  = (const float*)d_in[4 + l * 7 + 0];
        const float* bl  = (const float*)d_in[4 + l * 7 + 1];
        const float* wr  = (const float*)d_in[4 + l * 7 + 2];
        const float* br  = (const float*)d_in[4 + l * 7 + 3];
        const float* we  = (const float*)d_in[4 + l * 7 + 4];
        const float* att = (const float*)d_in[4 + l * 7 + 5];
        const float* cb  = (const float*)d_in[4 + l * 7 + 6];
        int H = (l == 3) ? 2 : 4;
        int C = (l == 0) ? 16 : 32;
        int HC = H * C;

        if (l == 0)      k_lin_t<5, 64>   <<<nblk, B, 0, stream>>>(hin, wl, bl, wr, br, xl16, xr, N);
        else if (l == 1) k_lin_t<64, 128> <<<nblk, B, 0, stream>>>(hin, wl, bl, wr, br, xl16, xr, N);
        else if (l == 2) k_lin_t<128, 128><<<nblk, B, 0, stream>>>(hin, wl, bl, wr, br, xl16, xr, N);
        else             k_lin_t<128, 64> <<<nblk, B, 0, stream>>>(hin, wl, bl, wr, br, xl16, xr, N);

        int npw = 64 / (HC / 2);
        int waves = (N + npw - 1) / npw;
        int blocks = (waves + 3) / 4;  // 4 waves per 256-thread block
        if (H == 4 && C == 16)
            k_fused<4, 16><<<blocks, B, 0, stream>>>(rowptr, csrc, cef, xl16, xr,
                                                     we, att, cb, houts[l], N);
        else if (H == 4 && C == 32)
            k_fused<4, 32><<<blocks, B, 0, stream>>>(rowptr, csrc, cef, xl16, xr,
                                                     we, att, cb, houts[l], N);
        else
            k_fused<2, 32><<<blocks, B, 0, stream>>>(rowptr, csrc, cef, xl16, xr,
                                                     we, att, cb, houts[l], N);
        hin = houts[l];
    }

    k_pool<<<(N + 31) / 32, B, 0, stream>>>(hin, batch, psum, pcnt, N);
    k_final<<<(G * 32 + TPB - 1) / TPB, B, 0, stream>>>(psum, pcnt,
                                                        (const float*)d_in[32],
                                                        (const float*)d_in[33],
                                                        (float*)d_out, G);
}